// Round 1
// baseline (164.387 us; speedup 1.0000x reference)
//
#include <hip/hip_runtime.h>
#include <hip/hip_bf16.h>

#define VOCAB 50257
#define EMBED 128
#define NSENT 50
#define TC 20
#define TQ 20
#define BATCH 64
#define NHOPS 3

typedef __bf16 bf16x8 __attribute__((ext_vector_type(8)));
typedef float  f32x4v __attribute__((ext_vector_type(4)));

// ---------------------------------------------------------------------------
// K1: embedding sums. One block per (batch, sentence) for m/c, plus 64 blocks
// for the question embedding u. 3264 blocks -> good CU coverage for the
// gather-bound phase.
// ---------------------------------------------------------------------------
__global__ void __launch_bounds__(256) k_embed(
    const int* __restrict__ stories, const int* __restrict__ masks,
    const int* __restrict__ questions,
    const float* __restrict__ W_A, const float* __restrict__ W_B,
    const float* __restrict__ W_C,
    const float* __restrict__ W_AT, const float* __restrict__ W_CT,
    float* __restrict__ ws_m, float* __restrict__ ws_c, float* __restrict__ ws_u)
{
    const int blk = blockIdx.x;
    const int tid = threadIdx.x;
    if (blk < BATCH * NSENT) {
        const int b = blk / NSENT;
        const int i = blk % NSENT;
        // temporal index: i+1 if any token has mask==0, else 0
        const int* mrow = masks + (b * NSENT + i) * TC;
        int cnt = 0;
        #pragma unroll
        for (int t = 0; t < TC; t++) cnt += (mrow[t] == 0);
        const int te = (cnt >= 1) ? (i + 1) : 0;

        const int* srow = stories + (b * NSENT + i) * TC;
        const int table = tid >> 7;      // waves 0,1 -> A/m ; waves 2,3 -> C/c
        const int d = tid & 127;
        const float* T  = table ? W_C  : W_A;
        const float* TT = table ? W_CT : W_AT;
        float acc = TT[te * EMBED + d];
        #pragma unroll
        for (int t = 0; t < TC; t++) {
            const int tok = srow[t];     // wave-uniform -> scalar load
            acc += T[tok * EMBED + d];   // 512B contiguous per row across 128 lanes
        }
        float* dst = table ? ws_c : ws_m;
        dst[(b * NSENT + i) * EMBED + d] = acc;
    } else {
        const int b = blk - BATCH * NSENT;
        if (tid < EMBED) {
            const int* qrow = questions + b * TQ;
            float acc = 0.f;
            #pragma unroll
            for (int t = 0; t < TQ; t++) acc += W_B[qrow[t] * EMBED + tid];
            ws_u[b * EMBED + tid] = acc;
        }
    }
}

// ---------------------------------------------------------------------------
// K2: 3 hops, one block per batch element, m/c staged in LDS (52 KB).
// Writes final u as bf16 in the A-fragment-friendly row-major layout.
// ---------------------------------------------------------------------------
__global__ void __launch_bounds__(256) k_hops(
    const float* __restrict__ ws_m, const float* __restrict__ ws_c,
    const float* __restrict__ ws_u, __bf16* __restrict__ ws_ubf)
{
    __shared__ float smc[2 * NSENT * EMBED];   // [0..6399]=m, [6400..12799]=c
    __shared__ float su[EMBED];
    __shared__ float sp[64];
    __shared__ float ssc[64];

    const int b = blockIdx.x;
    const int tid = threadIdx.x;

    const f32x4v* gm = (const f32x4v*)(ws_m + b * NSENT * EMBED);
    const f32x4v* gc = (const f32x4v*)(ws_c + b * NSENT * EMBED);
    f32x4v* s4 = (f32x4v*)smc;
    for (int idx = tid; idx < NSENT * EMBED / 4; idx += 256) {
        s4[idx] = gm[idx];
        s4[NSENT * EMBED / 4 + idx] = gc[idx];
    }
    if (tid < EMBED) su[tid] = ws_u[b * EMBED + tid];
    __syncthreads();

    const int wave = tid >> 6, lane = tid & 63;
    for (int hop = 0; hop < NHOPS; hop++) {
        // scores: one wave per sentence, shuffle reduce over 64 lanes
        for (int i = wave; i < NSENT; i += 4) {
            float s = smc[i * EMBED + lane] * su[lane]
                    + smc[i * EMBED + 64 + lane] * su[64 + lane];
            #pragma unroll
            for (int off = 32; off >= 1; off >>= 1) s += __shfl_xor(s, off);
            if (lane == 0) ssc[i] = s;
        }
        __syncthreads();
        // softmax over 50 sentences on wave 0
        if (tid < 64) {
            float v = (tid < NSENT) ? ssc[tid] : -1e30f;
            float mx = v;
            #pragma unroll
            for (int off = 32; off >= 1; off >>= 1) mx = fmaxf(mx, __shfl_xor(mx, off));
            float e = (tid < NSENT) ? expf(v - mx) : 0.f;
            float sum = e;
            #pragma unroll
            for (int off = 32; off >= 1; off >>= 1) sum += __shfl_xor(sum, off);
            sp[tid] = e / sum;
        }
        __syncthreads();
        // u += c^T probs
        if (tid < EMBED) {
            float o = 0.f;
            for (int i = 0; i < NSENT; i++)
                o += smc[NSENT * EMBED + i * EMBED + tid] * sp[i];
            su[tid] += o;
        }
        __syncthreads();
    }
    if (tid < EMBED) ws_ubf[b * EMBED + tid] = (__bf16)su[tid];
}

// ---------------------------------------------------------------------------
// K3: out[b][v] = u[b] . W_lin[v] + b_lin[v] via bf16 MFMA 16x16x32.
// Each wave: 16 v's x all 64 b (4 acc tiles). W_lin rows fetched exactly once,
// converted fp32->bf16 in-register.
// ---------------------------------------------------------------------------
__global__ void __launch_bounds__(256) k_out(
    const __bf16* __restrict__ u_bf, const float* __restrict__ W_lin,
    const float* __restrict__ b_lin, float* __restrict__ out)
{
    const int tid  = threadIdx.x;
    const int wave = tid >> 6, lane = tid & 63;
    const int m    = lane & 15;    // B-operand n (v within tile) / A-operand m
    const int quad = lane >> 4;
    const int v0   = blockIdx.x * 64 + wave * 16;
    const int v    = v0 + m;
    const int vc   = (v < VOCAB) ? v : (VOCAB - 1);

    f32x4v acc[4] = { {0.f,0.f,0.f,0.f}, {0.f,0.f,0.f,0.f},
                      {0.f,0.f,0.f,0.f}, {0.f,0.f,0.f,0.f} };

    const float* wrow = W_lin + (long)vc * EMBED;
    #pragma unroll
    for (int kc = 0; kc < 4; kc++) {
        const int k0 = kc * 32 + quad * 8;
        // B fragment: B[k=quad*8+j][n=m] = W_lin[v][k0+j], 8 contiguous floats
        f32x4v w0 = *(const f32x4v*)(wrow + k0);
        f32x4v w1 = *(const f32x4v*)(wrow + k0 + 4);
        bf16x8 wb;
        wb[0] = (__bf16)w0[0]; wb[1] = (__bf16)w0[1];
        wb[2] = (__bf16)w0[2]; wb[3] = (__bf16)w0[3];
        wb[4] = (__bf16)w1[0]; wb[5] = (__bf16)w1[1];
        wb[6] = (__bf16)w1[2]; wb[7] = (__bf16)w1[3];
        #pragma unroll
        for (int bt = 0; bt < 4; bt++) {
            // A fragment: A[m][k0+j] = u[bt*16+m][k0+j], 16B contiguous bf16
            bf16x8 ab = *(const bf16x8*)(u_bf + (bt * 16 + m) * EMBED + k0);
            acc[bt] = __builtin_amdgcn_mfma_f32_16x16x32_bf16(ab, wb, acc[bt], 0, 0, 0);
        }
    }

    const float bl = b_lin[vc];
    if (v < VOCAB) {
        #pragma unroll
        for (int bt = 0; bt < 4; bt++) {
            #pragma unroll
            for (int r = 0; r < 4; r++) {
                const int bb = bt * 16 + quad * 4 + r;   // C/D: row = quad*4+reg
                out[(long)bb * VOCAB + v] = acc[bt][r] + bl;
            }
        }
    }
}

extern "C" void kernel_launch(void* const* d_in, const int* in_sizes, int n_in,
                              void* d_out, int out_size, void* d_ws, size_t ws_size,
                              hipStream_t stream) {
    const int*   stories   = (const int*)d_in[0];
    const int*   questions = (const int*)d_in[1];
    const int*   masks     = (const int*)d_in[2];
    const float* W_A       = (const float*)d_in[3];
    const float* W_B       = (const float*)d_in[4];
    const float* W_C       = (const float*)d_in[5];
    const float* W_AT      = (const float*)d_in[6];
    const float* W_CT      = (const float*)d_in[7];
    const float* W_lin     = (const float*)d_in[8];
    const float* b_lin     = (const float*)d_in[9];
    float* out = (float*)d_out;

    float* ws    = (float*)d_ws;
    float* ws_m  = ws;                                   // 64*50*128 f32
    float* ws_c  = ws + BATCH * NSENT * EMBED;           // 64*50*128 f32
    float* ws_u  = ws + 2 * BATCH * NSENT * EMBED;       // 64*128 f32
    __bf16* ws_ubf = (__bf16*)(ws + 2 * BATCH * NSENT * EMBED + BATCH * EMBED);

    k_embed<<<dim3(BATCH * NSENT + BATCH), dim3(256), 0, stream>>>(
        stories, masks, questions, W_A, W_B, W_C, W_AT, W_CT, ws_m, ws_c, ws_u);
    k_hops<<<dim3(BATCH), dim3(256), 0, stream>>>(ws_m, ws_c, ws_u, ws_ubf);
    k_out<<<dim3((VOCAB + 63) / 64), dim3(256), 0, stream>>>(ws_ubf, W_lin, b_lin, out);
}